// Round 13
// baseline (378.106 us; speedup 1.0000x reference)
//
#include <hip/hip_runtime.h>
#include <hip/hip_bf16.h>

#define N_NODES 10000
#define N_EDGES 160000
#define TE1 32  // prep kernel edges/block
#define TE 64   // gemm kernel edges/block; 512 threads = 8 waves

typedef __attribute__((ext_vector_type(8))) short bfrag_t;   // 8 x bf16
typedef __attribute__((ext_vector_type(4))) float facc_t;    // 4 x f32

__device__ inline short f2bf(float f) {
    union { float f; unsigned u; } x; x.f = f;
    unsigned r = x.u + 0x7FFFu + ((x.u >> 16) & 1u);
    return (short)(r >> 16);
}

// Pack W2 (256x1024 f32, row-major) into MFMA B fragments, bf16, 1/16 folded.
__global__ void pack_w2(const float* __restrict__ w2, short* __restrict__ outp) {
    int g = blockIdx.x * blockDim.x + threadIdx.x;  // 0..262143
    int j    = g & 7;
    int lane = (g >> 3) & 63;
    int k    = (g >> 9) & 7;
    int nt   = (g >> 12) & 15;
    int p    = g >> 16;
    int row = k * 32 + ((lane >> 4) << 3) + j;
    int col = p * 256 + nt * 16 + (lane & 15);
    outp[g] = f2bf(w2[row * 1024 + col] * 0.0625f);
}

// ---- dst-sort infrastructure (unchanged, known-good) ----
__global__ void zero_counts(int* __restrict__ counts) {
    int i = blockIdx.x * blockDim.x + threadIdx.x;
    if (i < N_NODES) counts[i] = 0;
}

__global__ void hist_kernel(const int* __restrict__ edst, int* __restrict__ counts) {
    int e = blockIdx.x * blockDim.x + threadIdx.x;
    if (e < N_EDGES) atomicAdd(&counts[edst[e]], 1);
}

__global__ __launch_bounds__(256) void scan_kernel(const int* __restrict__ counts,
                                                   int* __restrict__ cursor) {
    __shared__ int part[256];
    const int t = threadIdx.x;
    const int CH = 40;
    int base = t * CH;
    int s = 0;
    for (int i = 0; i < CH; ++i) {
        int idx = base + i;
        if (idx < N_NODES) s += counts[idx];
    }
    part[t] = s;
    __syncthreads();
    for (int off = 1; off < 256; off <<= 1) {
        int add = (t >= off) ? part[t - off] : 0;
        __syncthreads();
        part[t] += add;
        __syncthreads();
    }
    int run = part[t] - s;
    for (int i = 0; i < CH; ++i) {
        int idx = base + i;
        if (idx < N_NODES) {
            cursor[idx] = run;
            run += counts[idx];
        }
    }
}

__global__ void scatter_kernel(const int* __restrict__ edst, int* __restrict__ cursor,
                               int* __restrict__ perm) {
    int e = blockIdx.x * blockDim.x + threadIdx.x;
    if (e < N_EDGES) {
        int pos = atomicAdd(&cursor[edst[e]], 1);
        perm[pos] = e;
    }
}

// ---- Kernel 1: prep. perm-gather edge data; compute h -> global (swizzle pre-baked) ----
__global__ __launch_bounds__(256) void prep_kernel(
    const int* __restrict__ perm,
    const int* __restrict__ esrc, const int* __restrict__ edst,
    const float* __restrict__ esh, const float* __restrict__ ell,
    const float* __restrict__ w1,
    int* __restrict__ gsrc, int* __restrict__ gdst, float* __restrict__ gsh,
    short* __restrict__ hg)
{
    __shared__ float el_lds[TE1][3];
    const int tid = threadIdx.x;
    const int e0  = blockIdx.x * TE1;

    if (tid < TE1) {
        int pe = perm[e0 + tid];
        gsrc[e0 + tid] = esrc[pe];
        gdst[e0 + tid] = edst[pe];
        float4 s4 = *(const float4*)(esh + (size_t)pe * 4);
        *(float4*)(gsh + (size_t)(e0 + tid) * 4) = s4;
        const float* lp = ell + (size_t)pe * 3;
        el_lds[tid][0] = lp[0]; el_lds[tid][1] = lp[1]; el_lds[tid][2] = lp[2];
    }
    __syncthreads();

    // h compute (r5/r12 phase-B code; endpoint = global, swizzled within 512B row)
    {
        int el = tid >> 3, c0 = (tid & 7) * 32;
        int eg = e0 + el;
        float l0 = el_lds[el][0], l1 = el_lds[el][1], l2 = el_lds[el][2];
        #pragma unroll
        for (int s = 0; s < 4; ++s) {
            bfrag_t hv;
            #pragma unroll
            for (int m = 0; m < 8; ++m) {
                int c = c0 + s * 8 + m;
                float a = l0 * w1[c] + l1 * w1[256 + c] + l2 * w1[512 + c];
                a = fmaxf(a, 0.f) * 0.8164965809277260f;  // sqrt(2/3), relu scale folded
                hv[m] = f2bf(a);
            }
            // same byte math as r12's LDS write: row*512 + (inrow ^ ((row&7)<<4))
            size_t byte = (size_t)eg * 512 + (((c0 + s * 8) * 2) ^ ((eg & 7) << 4));
            *(bfrag_t*)((char*)hg + byte) = hv;
        }
    }
}

// ---- Kernel 2: GEMM + TP + scatter (r12 phase C/D verbatim; A/B replaced by copies) ----
__global__ __launch_bounds__(512) void gemm_kernel(
    const int* __restrict__ gsrc, const int* __restrict__ gdst,
    const float* __restrict__ gsh, const short* __restrict__ hg,
    const float* __restrict__ nodef,
    const short* __restrict__ w2p, const int* __restrict__ nn,
    float* __restrict__ outg)
{
    __shared__ __align__(16) char hbuf[TE * 512];               // 32 KB
    short* h_lds  = (short*)hbuf;
    float* r0_lds = (float*)hbuf;                               // [64][17], 4352 B
    float* r1_lds = (float*)(hbuf + 4352);
    float* r2_lds = (float*)(hbuf + 8704);
    float* r3_lds = (float*)(hbuf + 13056);                     // [64][49], ends 25600
    __shared__ __align__(16) float x_lds[TE][68];               // 17408 B
    float* vbuf = (float*)x_lds;
    __shared__ float a0_lds[TE][17];
    __shared__ float a1_lds[TE][17];
    __shared__ float sh_lds[TE][4];
    __shared__ int   src_lds[TE];
    __shared__ int   dst_lds[TE];
    __shared__ int   head_lds[TE];

    const int tid = threadIdx.x;
    const int e0  = blockIdx.x * TE;

    // ---- phase A': coalesced edge loads ----
    if (tid < TE) {
        src_lds[tid] = gsrc[e0 + tid];
        dst_lds[tid] = gdst[e0 + tid];
        float4 s4 = *(const float4*)(gsh + (size_t)(e0 + tid) * 4);
        sh_lds[tid][0] = s4.x; sh_lds[tid][1] = s4.y;
        sh_lds[tid][2] = s4.z; sh_lds[tid][3] = s4.w;
    }
    __syncthreads();

    // x gather (r12 code) + h staging (linear copy; swizzle already baked in)
    {
        int e = tid >> 3, part = tid & 7;
        int s = src_lds[e];
        const float4* sp = (const float4*)(nodef + (size_t)s * 64 + part * 8);
        float4 u0 = sp[0], u1 = sp[1];
        float* xr = &x_lds[e][part * 8];
        *(float4*)(xr)     = u0;
        *(float4*)(xr + 4) = u1;
    }
    {
        // 64 rows x 512B = 32 KB; 512 threads x 64 B each
        const char* src = (const char*)hg + (size_t)e0 * 512;
        #pragma unroll
        for (int i = 0; i < 4; ++i) {
            int byte = tid * 64 + i * 16;
            *(float4*)(hbuf + byte) = *(const float4*)(src + byte);
        }
    }
    __syncthreads();
    {
        #pragma unroll
        for (int q = tid; q < TE * 16; q += 512) {
            int e = q >> 4, u = q & 15;
            float y0 = sh_lds[e][0];
            a0_lds[e][u] = x_lds[e][u] * y0;
            a1_lds[e][u] = x_lds[e][16 + u * 3 + 0] * sh_lds[e][1]
                         + x_lds[e][16 + u * 3 + 1] * sh_lds[e][2]
                         + x_lds[e][16 + u * 3 + 2] * sh_lds[e][3];
        }
    }
    __syncthreads();

    // ---- phase C: r12 verbatim (8 waves = path (wv&3) x m-half (wv>>2)) ----
    const int lane = tid & 63;
    const int wv   = tid >> 6;
    const int p    = wv & 3;
    const int mh   = wv >> 2;
    const int g    = lane >> 4;
    const int v    = lane & 15;
    const int eb   = 32 * mh;

    float acc0[2][4];
    float acc3[2][4][3];
    #pragma unroll
    for (int mt = 0; mt < 2; ++mt)
        #pragma unroll
        for (int r = 0; r < 4; ++r) {
            acc0[mt][r] = 0.f;
            acc3[mt][r][0] = 0.f; acc3[mt][r][1] = 0.f; acc3[mt][r][2] = 0.f;
        }

    const bfrag_t* Bp = (const bfrag_t*)w2p + (size_t)(p * 128) * 64 + lane;

    const int rb0 = (eb + v) * 512;
    const int rb1 = (eb + 16 + v) * 512;
    const int swz = (v & 7) << 4;

    #pragma unroll
    for (int ntc = 0; ntc < 4; ++ntc) {
        facc_t acc[2][4];
        #pragma unroll
        for (int mt = 0; mt < 2; ++mt)
            #pragma unroll
            for (int q = 0; q < 4; ++q)
                acc[mt][q] = (facc_t){0.f, 0.f, 0.f, 0.f};

        #pragma unroll
        for (int k = 0; k < 8; ++k) {
            int koff = (k * 32 + 8 * g) * 2;
            bfrag_t a0 = *(const bfrag_t*)((const char*)h_lds + ((rb0 + koff) ^ swz));
            bfrag_t a1 = *(const bfrag_t*)((const char*)h_lds + ((rb1 + koff) ^ swz));
            #pragma unroll
            for (int q = 0; q < 4; ++q) {
                bfrag_t b = Bp[(size_t)((ntc * 4 + q) * 8 + k) * 64];
                acc[0][q] = __builtin_amdgcn_mfma_f32_16x16x32_bf16(a0, b, acc[0][q], 0, 0, 0);
                acc[1][q] = __builtin_amdgcn_mfma_f32_16x16x32_bf16(a1, b, acc[1][q], 0, 0, 0);
            }
        }
        #pragma unroll
        for (int mt = 0; mt < 2; ++mt)
            #pragma unroll
            for (int r = 0; r < 4; ++r) {
                int e = eb + mt * 16 + 4 * g + r;
                #pragma unroll
                for (int q = 0; q < 4; ++q) {
                    int u = ntc * 4 + q;
                    float wvl = acc[mt][q][r];
                    if (p == 0)       acc0[mt][r] += a0_lds[e][u] * wvl;
                    else if (p == 1)  acc0[mt][r] += a1_lds[e][u] * wvl;
                    else if (p == 2)  acc0[mt][r] += x_lds[e][u] * wvl;
                    else {
                        acc3[mt][r][0] += x_lds[e][16 + u * 3 + 0] * wvl;
                        acc3[mt][r][1] += x_lds[e][16 + u * 3 + 1] * wvl;
                        acc3[mt][r][2] += x_lds[e][16 + u * 3 + 2] * wvl;
                    }
                }
            }
    }

    __syncthreads();   // ALL h_lds reads complete -> r* may overwrite hbuf

    #pragma unroll
    for (int mt = 0; mt < 2; ++mt)
        #pragma unroll
        for (int r = 0; r < 4; ++r) {
            int e = eb + mt * 16 + 4 * g + r;
            if (p == 0)       r0_lds[e * 17 + v] = acc0[mt][r];
            else if (p == 1)  r1_lds[e * 17 + v] = acc0[mt][r];
            else if (p == 2)  r2_lds[e * 17 + v] = acc0[mt][r];
            else {
                r3_lds[e * 49 + v * 3 + 0] = acc3[mt][r][0];
                r3_lds[e * 49 + v * 3 + 1] = acc3[mt][r][1];
                r3_lds[e * 49 + v * 3 + 2] = acc3[mt][r][2];
            }
        }
    __syncthreads();

    // ---- phase D: r12 verbatim ----
    {
        float scale = rsqrtf((float)nn[0]);
        const float pw0 = 0.17677669529663687f;
        float k0 = pw0 * scale;
        float k1 = k0 * 0.57735026918962576f;

        int e  = tid >> 3;
        int j0 = (tid & 7) * 8;
        float y0  = sh_lds[e][0];
        float y1x = sh_lds[e][1], y1y = sh_lds[e][2], y1z = sh_lds[e][3];
        #pragma unroll
        for (int jj = 0; jj < 8; ++jj) {
            int j = j0 + jj;
            float val;
            if (j < 16) {
                val = k0 * r0_lds[e * 17 + j] + k1 * r1_lds[e * 17 + j];
            } else {
                int t2 = j - 16;
                int vv = t2 / 3;
                int i  = t2 - vv * 3;
                float y1i = (i == 0) ? y1x : ((i == 1) ? y1y : y1z);
                val = k0 * (y1i * r2_lds[e * 17 + vv] + y0 * r3_lds[e * 49 + t2]);
            }
            vbuf[e * 68 + j] = val;
        }
    }
    if (tid < TE)
        head_lds[tid] = (tid == 0) || (dst_lds[tid] != dst_lds[tid - 1]);
    __syncthreads();
    {
        int e   = tid >> 3;
        int oct = tid & 7;
        if (head_lds[e]) {
            int L = 1;
            while (e + L < TE && !head_lds[e + L]) ++L;
            float4 s0 = *(const float4*)(vbuf + e * 68 + oct * 8);
            float4 s1 = *(const float4*)(vbuf + e * 68 + oct * 8 + 4);
            for (int i = 1; i < L; ++i) {
                const float4* q = (const float4*)(vbuf + (e + i) * 68 + oct * 8);
                float4 t0 = q[0], t1 = q[1];
                s0.x += t0.x; s0.y += t0.y; s0.z += t0.z; s0.w += t0.w;
                s1.x += t1.x; s1.y += t1.y; s1.z += t1.z; s1.w += t1.w;
            }
            float* op = outg + (size_t)dst_lds[e] * 64 + oct * 8;
            atomicAdd(op + 0, s0.x); atomicAdd(op + 1, s0.y);
            atomicAdd(op + 2, s0.z); atomicAdd(op + 3, s0.w);
            atomicAdd(op + 4, s1.x); atomicAdd(op + 5, s1.y);
            atomicAdd(op + 6, s1.z); atomicAdd(op + 7, s1.w);
        }
    }
}

// ---- Fallback: r12 conv_kernel verbatim (used if ws too small for the split) ----
__global__ __launch_bounds__(512) void conv_kernel(
    const int* __restrict__ perm,
    const int* __restrict__ esrc, const int* __restrict__ edst,
    const float* __restrict__ nodef, const float* __restrict__ esh,
    const float* __restrict__ ell, const float* __restrict__ w1,
    const short* __restrict__ w2p, const int* __restrict__ nn,
    float* __restrict__ outg)
{
    __shared__ __align__(16) char hbuf[TE * 512];
    short* h_lds  = (short*)hbuf;
    float* r0_lds = (float*)hbuf;
    float* r1_lds = (float*)(hbuf + 4352);
    float* r2_lds = (float*)(hbuf + 8704);
    float* r3_lds = (float*)(hbuf + 13056);
    __shared__ __align__(16) float x_lds[TE][68];
    float* vbuf = (float*)x_lds;
    __shared__ float a0_lds[TE][17];
    __shared__ float a1_lds[TE][17];
    __shared__ float sh_lds[TE][4];
    __shared__ float el_lds[TE][3];
    __shared__ int   src_lds[TE];
    __shared__ int   dst_lds[TE];
    __shared__ int   head_lds[TE];

    const int tid = threadIdx.x;
    const int e0  = blockIdx.x * TE;

    if (tid < TE) {
        int pe = perm[e0 + tid];
        src_lds[tid] = esrc[pe];
        dst_lds[tid] = edst[pe];
        float4 s4 = *(const float4*)(esh + (size_t)pe * 4);
        sh_lds[tid][0] = s4.x; sh_lds[tid][1] = s4.y;
        sh_lds[tid][2] = s4.z; sh_lds[tid][3] = s4.w;
        const float* lp = ell + (size_t)pe * 3;
        el_lds[tid][0] = lp[0]; el_lds[tid][1] = lp[1]; el_lds[tid][2] = lp[2];
    }
    __syncthreads();

    {
        int e = tid >> 3, part = tid & 7;
        int s = src_lds[e];
        const float4* sp = (const float4*)(nodef + (size_t)s * 64 + part * 8);
        float4 u0 = sp[0], u1 = sp[1];
        float* xr = &x_lds[e][part * 8];
        *(float4*)(xr)     = u0;
        *(float4*)(xr + 4) = u1;
    }
    {
        int e = tid >> 3, c0 = (tid & 7) * 32;
        float l0 = el_lds[e][0], l1 = el_lds[e][1], l2 = el_lds[e][2];
        #pragma unroll
        for (int s = 0; s < 4; ++s) {
            bfrag_t hv;
            #pragma unroll
            for (int m = 0; m < 8; ++m) {
                int c = c0 + s * 8 + m;
                float a = l0 * w1[c] + l1 * w1[256 + c] + l2 * w1[512 + c];
                a = fmaxf(a, 0.f) * 0.8164965809277260f;
                hv[m] = f2bf(a);
            }
            int byte = (e * 512 + (c0 + s * 8) * 2) ^ ((e & 7) << 4);
            *(bfrag_t*)((char*)h_lds + byte) = hv;
        }
    }
    __syncthreads();
    {
        #pragma unroll
        for (int q = tid; q < TE * 16; q += 512) {
            int e = q >> 4, u = q & 15;
            float y0 = sh_lds[e][0];
            a0_lds[e][u] = x_lds[e][u] * y0;
            a1_lds[e][u] = x_lds[e][16 + u * 3 + 0] * sh_lds[e][1]
                         + x_lds[e][16 + u * 3 + 1] * sh_lds[e][2]
                         + x_lds[e][16 + u * 3 + 2] * sh_lds[e][3];
        }
    }
    __syncthreads();

    const int lane = tid & 63;
    const int wv   = tid >> 6;
    const int p    = wv & 3;
    const int mh   = wv >> 2;
    const int g    = lane >> 4;
    const int v    = lane & 15;
    const int eb   = 32 * mh;

    float acc0[2][4];
    float acc3[2][4][3];
    #pragma unroll
    for (int mt = 0; mt < 2; ++mt)
        #pragma unroll
        for (int r = 0; r < 4; ++r) {
            acc0[mt][r] = 0.f;
            acc3[mt][r][0] = 0.f; acc3[mt][r][1] = 0.f; acc3[mt][r][2] = 0.f;
        }

    const bfrag_t* Bp = (const bfrag_t*)w2p + (size_t)(p * 128) * 64 + lane;
    const int rb0 = (eb + v) * 512;
    const int rb1 = (eb + 16 + v) * 512;
    const int swz = (v & 7) << 4;

    #pragma unroll
    for (int ntc = 0; ntc < 4; ++ntc) {
        facc_t acc[2][4];
        #pragma unroll
        for (int mt = 0; mt < 2; ++mt)
            #pragma unroll
            for (int q = 0; q < 4; ++q)
                acc[mt][q] = (facc_t){0.f, 0.f, 0.f, 0.f};

        #pragma unroll
        for (int k = 0; k < 8; ++k) {
            int koff = (k * 32 + 8 * g) * 2;
            bfrag_t a0 = *(const bfrag_t*)((const char*)h_lds + ((rb0 + koff) ^ swz));
            bfrag_t a1 = *(const bfrag_t*)((const char*)h_lds + ((rb1 + koff) ^ swz));
            #pragma unroll
            for (int q = 0; q < 4; ++q) {
                bfrag_t b = Bp[(size_t)((ntc * 4 + q) * 8 + k) * 64];
                acc[0][q] = __builtin_amdgcn_mfma_f32_16x16x32_bf16(a0, b, acc[0][q], 0, 0, 0);
                acc[1][q] = __builtin_amdgcn_mfma_f32_16x16x32_bf16(a1, b, acc[1][q], 0, 0, 0);
            }
        }
        #pragma unroll
        for (int mt = 0; mt < 2; ++mt)
            #pragma unroll
            for (int r = 0; r < 4; ++r) {
                int e = eb + mt * 16 + 4 * g + r;
                #pragma unroll
                for (int q = 0; q < 4; ++q) {
                    int u = ntc * 4 + q;
                    float wvl = acc[mt][q][r];
                    if (p == 0)       acc0[mt][r] += a0_lds[e][u] * wvl;
                    else if (p == 1)  acc0[mt][r] += a1_lds[e][u] * wvl;
                    else if (p == 2)  acc0[mt][r] += x_lds[e][u] * wvl;
                    else {
                        acc3[mt][r][0] += x_lds[e][16 + u * 3 + 0] * wvl;
                        acc3[mt][r][1] += x_lds[e][16 + u * 3 + 1] * wvl;
                        acc3[mt][r][2] += x_lds[e][16 + u * 3 + 2] * wvl;
                    }
                }
            }
    }

    __syncthreads();

    #pragma unroll
    for (int mt = 0; mt < 2; ++mt)
        #pragma unroll
        for (int r = 0; r < 4; ++r) {
            int e = eb + mt * 16 + 4 * g + r;
            if (p == 0)       r0_lds[e * 17 + v] = acc0[mt][r];
            else if (p == 1)  r1_lds[e * 17 + v] = acc0[mt][r];
            else if (p == 2)  r2_lds[e * 17 + v] = acc0[mt][r];
            else {
                r3_lds[e * 49 + v * 3 + 0] = acc3[mt][r][0];
                r3_lds[e * 49 + v * 3 + 1] = acc3[mt][r][1];
                r3_lds[e * 49 + v * 3 + 2] = acc3[mt][r][2];
            }
        }
    __syncthreads();

    {
        float scale = rsqrtf((float)nn[0]);
        const float pw0 = 0.17677669529663687f;
        float k0 = pw0 * scale;
        float k1 = k0 * 0.57735026918962576f;

        int e  = tid >> 3;
        int j0 = (tid & 7) * 8;
        float y0  = sh_lds[e][0];
        float y1x = sh_lds[e][1], y1y = sh_lds[e][2], y1z = sh_lds[e][3];
        #pragma unroll
        for (int jj = 0; jj < 8; ++jj) {
            int j = j0 + jj;
            float val;
            if (j < 16) {
                val = k0 * r0_lds[e * 17 + j] + k1 * r1_lds[e * 17 + j];
            } else {
                int t2 = j - 16;
                int vv = t2 / 3;
                int i  = t2 - vv * 3;
                float y1i = (i == 0) ? y1x : ((i == 1) ? y1y : y1z);
                val = k0 * (y1i * r2_lds[e * 17 + vv] + y0 * r3_lds[e * 49 + t2]);
            }
            vbuf[e * 68 + j] = val;
        }
    }
    if (tid < TE)
        head_lds[tid] = (tid == 0) || (dst_lds[tid] != dst_lds[tid - 1]);
    __syncthreads();
    {
        int e   = tid >> 3;
        int oct = tid & 7;
        if (head_lds[e]) {
            int L = 1;
            while (e + L < TE && !head_lds[e + L]) ++L;
            float4 s0 = *(const float4*)(vbuf + e * 68 + oct * 8);
            float4 s1 = *(const float4*)(vbuf + e * 68 + oct * 8 + 4);
            for (int i = 1; i < L; ++i) {
                const float4* q = (const float4*)(vbuf + (e + i) * 68 + oct * 8);
                float4 t0 = q[0], t1 = q[1];
                s0.x += t0.x; s0.y += t0.y; s0.z += t0.z; s0.w += t0.w;
                s1.x += t1.x; s1.y += t1.y; s1.z += t1.z; s1.w += t1.w;
            }
            float* op = outg + (size_t)dst_lds[e] * 64 + oct * 8;
            atomicAdd(op + 0, s0.x); atomicAdd(op + 1, s0.y);
            atomicAdd(op + 2, s0.z); atomicAdd(op + 3, s0.w);
            atomicAdd(op + 4, s1.x); atomicAdd(op + 5, s1.y);
            atomicAdd(op + 6, s1.z); atomicAdd(op + 7, s1.w);
        }
    }
}

extern "C" void kernel_launch(void* const* d_in, const int* in_sizes, int n_in,
                              void* d_out, int out_size, void* d_ws, size_t ws_size,
                              hipStream_t stream) {
    const int*   esrc  = (const int*)d_in[0];
    const int*   edst  = (const int*)d_in[1];
    const float* nodef = (const float*)d_in[2];
    const float* esh   = (const float*)d_in[3];
    const float* ellv  = (const float*)d_in[4];
    const float* w1    = (const float*)d_in[5];
    const float* w2    = (const float*)d_in[6];
    const int*   nn    = (const int*)d_in[7];
    float* outg = (float*)d_out;

    char* ws = (char*)d_ws;
    size_t off = 0;
    auto alloc = [&](size_t sz) { size_t r = off; off = (off + sz + 4095) & ~(size_t)4095; return r; };
    size_t o_w2p  = alloc(524288);
    size_t o_cnt  = alloc(40960);
    size_t o_cur  = alloc(40960);
    size_t o_perm = alloc((size_t)N_EDGES * 4);
    size_t o_gsrc = alloc((size_t)N_EDGES * 4);
    size_t o_gdst = alloc((size_t)N_EDGES * 4);
    size_t o_gsh  = alloc((size_t)N_EDGES * 16);
    size_t o_hg   = alloc((size_t)N_EDGES * 512);
    int use_split = (ws_size >= off);

    short* w2p    = (short*)(ws + o_w2p);
    int*   counts = (int*)(ws + o_cnt);
    int*   cursor = (int*)(ws + o_cur);
    int*   permv  = (int*)(ws + o_perm);

    hipMemsetAsync(d_out, 0, (size_t)out_size * sizeof(float), stream);
    pack_w2<<<1024, 256, 0, stream>>>(w2, w2p);
    zero_counts<<<(N_NODES + 255) / 256, 256, 0, stream>>>(counts);
    hist_kernel<<<N_EDGES / 256, 256, 0, stream>>>(edst, counts);
    scan_kernel<<<1, 256, 0, stream>>>(counts, cursor);
    scatter_kernel<<<N_EDGES / 256, 256, 0, stream>>>(edst, cursor, permv);

    if (use_split) {
        int*   gsrc = (int*)(ws + o_gsrc);
        int*   gdst = (int*)(ws + o_gdst);
        float* gsh  = (float*)(ws + o_gsh);
        short* hg   = (short*)(ws + o_hg);
        prep_kernel<<<N_EDGES / TE1, 256, 0, stream>>>(permv, esrc, edst, esh, ellv, w1,
                                                       gsrc, gdst, gsh, hg);
        gemm_kernel<<<N_EDGES / TE, 512, 0, stream>>>(gsrc, gdst, gsh, hg, nodef,
                                                      w2p, nn, outg);
    } else {
        conv_kernel<<<N_EDGES / TE, 512, 0, stream>>>(permv, esrc, edst, nodef, esh, ellv,
                                                      w1, w2p, nn, outg);
    }
}